// Round 19
// baseline (481.353 us; speedup 1.0000x reference)
//
#include <hip/hip_runtime.h>
#include <hip/hip_bf16.h>
#include <cstdint>

typedef __attribute__((ext_vector_type(8))) __bf16 bf16x8;
typedef __attribute__((ext_vector_type(4))) float f32x4;
typedef unsigned short u16;

#define B_    2
#define S_    2048
#define D_    3584
#define H_    28
#define KVH_  4
#define HD_   128
#define GQA_  7
#define QKVN  4608
// SCALE * log2(e): Q pre-scaled for exp2-domain softmax
#define QK2SCALE 0.12751744416014806f

#define WAITV(N) asm volatile("s_waitcnt vmcnt(" #N ")" ::: "memory")
#define WAITL(N) asm volatile("s_waitcnt lgkmcnt(" #N ")" ::: "memory")

__device__ __forceinline__ u16 f2bf(float f){
  union { float f; uint32_t u; } v; v.f = f;
  uint32_t u = v.u + 0x7fffu + ((v.u >> 16) & 1u);   // RNE
  return (u16)(u >> 16);
}
__device__ __forceinline__ float bf2f(u16 h){
  union { uint32_t u; float f; } v; v.u = ((uint32_t)h) << 16; return v.f;
}
__device__ __forceinline__ float exp2a(float x){       // v_exp_f32: D = 2^S0
  float r; asm("v_exp_f32 %0, %1" : "=v"(r) : "v"(x)); return r;
}
__device__ __forceinline__ uint32_t cvtpk(float lo, float hi){  // 2x f32 -> packed bf16 (RNE)
  uint32_t r; asm("v_cvt_pk_bf16_f32 %0, %1, %2" : "=v"(r) : "v"(lo), "v"(hi)); return r;
}

typedef void __attribute__((address_space(1))) as1void;
typedef void __attribute__((address_space(3))) as3void;
__device__ __forceinline__ void gload16(const void* g, void* l){
  __builtin_amdgcn_global_load_lds((as1void*)g, (as3void*)l, 16, 0, 0);
}

// ---------------- fused prep: convx | tconv x4 | rope tables, one launch ----------------
#define NB_CONVX 14336      // MB*D/4/256
#define NB_WQ    12544      // (3584/32)*(3584/32)
#define NB_WK    1792       // (512/32)*(3584/32)
#define NB_WV    1792
#define NB_WO    12544
#define NB_TAB   512        // S*64/256
__global__ __launch_bounds__(256) void prep_kernel(const float* __restrict__ X, u16* __restrict__ Xb,
                                                   const float* __restrict__ Wq, const float* __restrict__ Wk,
                                                   const float* __restrict__ Wv, const float* __restrict__ Wo,
                                                   u16* __restrict__ Wqkv, u16* __restrict__ Wot,
                                                   float* __restrict__ cost, float* __restrict__ sint){
  __shared__ float t[32][33];
  int id = blockIdx.x;
  if (id < NB_CONVX){                       // X f32 -> bf16
    int i = id*256 + threadIdx.x;
    float4 v = ((const float4*)X)[i];
    ushort4 o; o.x=f2bf(v.x); o.y=f2bf(v.y); o.z=f2bf(v.z); o.w=f2bf(v.w);
    ((ushort4*)Xb)[i] = o;
    return;
  }
  id -= NB_CONVX;
  if (id < NB_WQ + NB_WK + NB_WV + NB_WO){  // transpose+convert a weight tile
    const float* src; u16* dst; int R, C;
    if (id < NB_WQ){ src = Wq; dst = Wqkv; R = D_; C = H_*HD_; }
    else if (id < NB_WQ + NB_WK){ id -= NB_WQ; src = Wk; dst = Wqkv + (size_t)(H_*HD_)*D_; R = D_; C = KVH_*HD_; }
    else if (id < NB_WQ + NB_WK + NB_WV){ id -= NB_WQ + NB_WK; src = Wv; dst = Wqkv + (size_t)(H_*HD_ + KVH_*HD_)*D_; R = D_; C = KVH_*HD_; }
    else { id -= NB_WQ + NB_WK + NB_WV; src = Wo; dst = Wot; R = H_*HD_; C = D_; }
    int nbx = C >> 5;
    int c0 = (id % nbx) << 5, r0 = (id / nbx) << 5;
    int r = threadIdx.x >> 5, c = threadIdx.x & 31;
    #pragma unroll
    for (int i=0;i<4;i++) t[r+8*i][c] = src[(size_t)(r0 + r + 8*i)*C + c0 + c];
    __syncthreads();
    #pragma unroll
    for (int i=0;i<4;i++) dst[(size_t)(c0 + r + 8*i)*R + r0 + c] = f2bf(t[c][r+8*i]);
    return;
  }
  id -= NB_WQ + NB_WK + NB_WV + NB_WO;      // rope tables
  int i = id*256 + threadIdx.x;             // S_*64
  int s = i >> 6, d = i & 63;
  float inv = powf(1.0e6f, -(float)d * (1.0f/64.0f));
  float a = (float)s * inv;
  cost[i] = cosf(a); sint[i] = sinf(a);
}

// ---------------- transpose bf16 (V slice of QKV): per-batch [R][C] (row stride instride) -> [C][R] ----------------
__global__ __launch_bounds__(256) void tbf16_kernel(const u16* __restrict__ in, u16* __restrict__ outp, int R, int C, int instride){
  const u16* inb = in + (size_t)blockIdx.z*R*instride;
  u16* outb = outp + (size_t)blockIdx.z*R*C;
  __shared__ u16 t[32][33];
  int r = threadIdx.x >> 5, c = threadIdx.x & 31;
  int r0 = blockIdx.y*32, c0 = blockIdx.x*32;
  #pragma unroll
  for (int i=0;i<4;i++) t[r+8*i][c] = inb[(size_t)(r0+r+8*i)*instride + c0+c];
  __syncthreads();
  #pragma unroll
  for (int i=0;i<4;i++) outb[(size_t)(c0+r+8*i)*R + r0+c] = t[c][r+8*i];
}

// ---------------- 128x128 4-wave GEMM, dbuf + counted vmcnt, multi-block/CU ----------------
// The empirically fastest GEMM structure this session (r18): 32KB LDS dbuf -> 3-4 blocks/CU,
// WAITV(4) keeps next tile's 4 gloads in flight across the barrier; cross-block overlap hides
// the barrier drain. Optional rope epilogue (pairs (d,d+64) intra-lane via the B-fragment col
// map col(f) = wc*32 + (f>>1)*64 + (f&1)*16 + lm), with runtime scale (Q: QK2SCALE, K: 1.0).
template<bool OUTF32, bool ROPE>
__global__ __launch_bounds__(256) void gemm128_kernel(const u16* __restrict__ A, const u16* __restrict__ Bt,
                                                      void* __restrict__ Cv, int M, int N, int K, int ldc, int coloff,
                                                      const float* __restrict__ cost, const float* __restrict__ sint,
                                                      int ropeNmax, float ropescale){
  __shared__ char lds[32768];   // buf c at c*16384: A[128][32] (8KB) | B[128][32] (8KB)
  const int tid = threadIdx.x;
  const int l = tid & 63, lg = l >> 4, lm = l & 15;
  const int w = tid >> 6, wr = w >> 1, wc = w & 1;
  const int m0 = blockIdx.y * 128, n0 = blockIdx.x * 128;

  f32x4 acc[4][4];
  #pragma unroll
  for (int m=0;m<4;++m)
    #pragma unroll
    for (int n=0;n<4;++n) acc[m][n] = (f32x4){0.f,0.f,0.f,0.f};

  auto stage = [&](int T){      // 4 gloads
    const int kb = T << 5;
    char* base = lds + (size_t)(T & 1)*16384;
    #pragma unroll
    for (int j = 0; j < 2; ++j){
      int g = j*256 + tid;
      int row = g >> 2, wi = g & 3;
      int ksrc = kb + ((wi ^ (row & 3)) << 3);
      gload16(A  + (size_t)(m0+row)*K + ksrc, base + j*4096 + (tid & 192)*16);
      gload16(Bt + (size_t)(n0+row)*K + ksrc, base + 8192 + j*4096 + (tid & 192)*16);
    }
  };

  const int nkt = K >> 5;
  stage(0); stage(1);           // 8 loads outstanding
  int cur = 0;
  for (int t = 0; t < nkt; ++t){
    if (t + 1 < nkt){ WAITV(4); }   // tile t landed; t+1's 4 in flight
    else            { WAITV(0); }
    __builtin_amdgcn_s_barrier();
    const char* As = lds + (size_t)cur*16384;
    const char* Bs = As + 8192;
    bf16x8 af[4], bfr[4];
    #pragma unroll
    for (int m = 0; m < 4; ++m){
      int r = wr*64 + m*16 + lm;
      af[m] = *(const bf16x8*)(As + r*64 + ((lg ^ (r & 3)) << 4));
    }
    #pragma unroll
    for (int n = 0; n < 4; ++n){
      int r = (wc<<5) + ((n>>1)<<6) + ((n&1)<<4) + lm;
      bfr[n] = *(const bf16x8*)(Bs + r*64 + ((lg ^ (r & 3)) << 4));
    }
    __builtin_amdgcn_s_setprio(1);
    #pragma unroll
    for (int m = 0; m < 4; ++m)
      #pragma unroll
      for (int n = 0; n < 4; ++n)
        acc[m][n] = __builtin_amdgcn_mfma_f32_16x16x32_bf16(af[m], bfr[n], acc[m][n], 0,0,0);
    __builtin_amdgcn_s_setprio(0);
    WAITL(0);                       // this wave's ds reads drained
    __builtin_amdgcn_s_barrier();   // all waves -> safe to overwrite buf[cur]
    if (t + 2 < nkt) stage(t+2);
    cur ^= 1;
  }

  // rope epilogue: pairs acc[m][n]/acc[m][n+2], d = wc*32 + n*16 + lm (each 128-col block = 1 head)
  if (ROPE && n0 < ropeNmax){
    #pragma unroll
    for (int m=0;m<4;++m)
      #pragma unroll
      for (int n=0;n<2;++n)
        #pragma unroll
        for (int r=0;r<4;++r){
          int row = m0 + wr*64 + m*16 + lg*4 + r;
          int s = row & (S_-1);
          int d = (wc<<5) + (n<<4) + lm;
          float cv = cost[s*64+d], sv = sint[s*64+d];
          float lo = acc[m][n][r], hi = acc[m][n+2][r];
          acc[m][n][r]   = (lo*cv - hi*sv)*ropescale;
          acc[m][n+2][r] = (hi*cv + lo*sv)*ropescale;
        }
  }

  #pragma unroll
  for (int m=0;m<4;++m)
    #pragma unroll
    for (int n=0;n<4;++n)
      #pragma unroll
      for (int r=0;r<4;++r){
        int row = m0 + wr*64 + m*16 + lg*4 + r;
        int col = coloff + n0 + (wc<<5) + ((n>>1)<<6) + ((n&1)<<4) + lm;
        if (OUTF32) ((float*)Cv)[(size_t)row*ldc + col] = acc[m][n][r];
        else        ((u16*)Cv)[(size_t)row*ldc + col] = f2bf(acc[m][n][r]);
      }
}

// ---------------- flash attention, causal, GQA (round-17, unchanged) ----------------
__global__ __launch_bounds__(512, 4) void attn_kernel(const u16* __restrict__ QKV, const u16* __restrict__ Vt,
                                                      u16* __restrict__ O){
  __shared__ u16 Kl[2][8192];   // [buf][kp(64)][d(128)], XOR-swizzled granules (16/row, ^kp&7)
  __shared__ u16 Vl[8192];      // [d(128)][kp(64)], swizzled (8/row, ^d&7), single buffer
  const int id = blockIdx.x;
  const int qt = (S_/128 - 1) - id/(H_*B_);     // reversed: heavy tiles dispatch first
  const int hb = id % (H_*B_);
  const int h = hb % H_, b = hb / H_;
  const int kvh = h / GQA_;
  const int tid = threadIdx.x;
  const int w = tid >> 6, l = tid & 63, lg = l >> 4, lm = l & 15;

  const int qrowA = qt*128 + w*16 + lm;       // the q-row whose fragment this lane carries
  const u16* qptr = QKV + (size_t)(b*S_ + qrowA)*QKVN + h*HD_;
  bf16x8 qf[4];
  #pragma unroll
  for (int ks = 0; ks < 4; ++ks) qf[ks] = *(const bf16x8*)(qptr + ks*32 + lg*8);
  WAITV(0);
  asm volatile("" :: "v"(qf[0]), "v"(qf[1]), "v"(qf[2]), "v"(qf[3]));

  const int qcol  = qrowA;                    // this lane's q in swapped-S space
  const int qrowD = qt*128 + w*16 + lg*4;     // output rows (PV D-layout), +r
  float m_run = -3.0e38f, l_run = 0.0f;
  f32x4 oacc[8];
  #pragma unroll
  for (int dn=0;dn<8;++dn) oacc[dn] = (f32x4){0.f,0.f,0.f,0.f};

  const u16* Kbase = QKV + (size_t)(b*S_)*QKVN + H_*HD_ + kvh*HD_;
  const u16* Vbase = Vt + (size_t)(b*KVH_ + kvh)*HD_*S_;

  auto stageK = [&](int bufi, int ktv){
    const int kb = ktv*64;
    #pragma unroll
    for (int j = 0; j < 2; ++j){
      int g = j*512 + tid;
      int kp = g >> 4, wik = g & 15;
      gload16(Kbase + (size_t)(kb + kp)*QKVN + (wik ^ (kp & 7))*8,
              (char*)Kl + bufi*16384 + j*8192 + (tid & 448)*16);
    }
  };
  auto stageV = [&](int ktv){
    const int kb = ktv*64;
    #pragma unroll
    for (int j = 0; j < 2; ++j){
      int g = j*512 + tid;
      int dd = g >> 3, wiv = g & 7;
      gload16(Vbase + (size_t)dd*S_ + kb + (wiv ^ (dd & 7))*8,
              (char*)Vl + j*8192 + (tid & 448)*16);
    }
  };

  const int nkt = 2*qt + 2;
  int cur = 0;
  stageK(0, 0); stageV(0); stageK(1, 1);

  auto iter = [&](int kt, bool domask){
    const bool last = (kt + 1 == nkt);
    // top: drain K(kt) only; V(kt) and K(kt+1) remain in flight
    if (last) WAITV(2); else WAITV(4);
    __builtin_amdgcn_s_barrier();
    const int cb = cur*16384;

    // ---- QK^T, SWAPPED: sf[n][r] = S[kp = n*16+lg*4+r][q = qcol] ----
    f32x4 sf[4];
    __builtin_amdgcn_s_setprio(1);
    #pragma unroll
    for (int n = 0; n < 4; ++n){
      sf[n] = (f32x4){0.f,0.f,0.f,0.f};
      int kp = n*16 + lm;
      #pragma unroll
      for (int ks = 0; ks < 4; ++ks){
        bf16x8 kf = *(const bf16x8*)((const char*)Kl + cb + kp*256 + (((ks*4 + lg) ^ (kp & 7))*16));
        sf[n] = __builtin_amdgcn_mfma_f32_16x16x32_bf16(kf, qf[ks], sf[n], 0,0,0);
      }
    }
    __builtin_amdgcn_s_setprio(0);

    // ---- softmax: lane owns 16 scores of row q=qcol ----
    float p[4][4];
    float rmax = -3.0e38f;
    #pragma unroll
    for (int n=0;n<4;++n)
      #pragma unroll
      for (int r=0;r<4;++r){
        float v = sf[n][r];
        if (domask && (kt*64 + n*16 + lg*4 + r) > qcol) v -= 1.0e9f;
        p[n][r] = v;
        rmax = fmaxf(rmax, v);
      }
    rmax = fmaxf(rmax, __shfl_xor(rmax, 16, 64));
    rmax = fmaxf(rmax, __shfl_xor(rmax, 32, 64));

    // thresholded defer-max: rescale only when growth exceeds 8 (exp2 domain)
    if (__any(rmax > m_run + 8.0f)){
      float mn = fmaxf(m_run, rmax);
      float corr = exp2a(m_run - mn);
      m_run = mn;
      l_run *= corr;
      float corr_r[4];
      #pragma unroll
      for (int r=0;r<4;++r) corr_r[r] = __shfl(corr, lg*4 + r, 64);
      #pragma unroll
      for (int dn=0;dn<8;++dn)
        #pragma unroll
        for (int r=0;r<4;++r) oacc[dn][r] *= corr_r[r];
    }
    float psum = 0.f;
    #pragma unroll
    for (int n=0;n<4;++n)
      #pragma unroll
      for (int r=0;r<4;++r){ p[n][r] = exp2a(p[n][r] - m_run); psum += p[n][r]; }
    l_run += psum;

    // ---- V(kt) drained (own loads), then barrier: Kl[cur] dead for aliasing AND all waves' V visible ----
    if (last) WAITV(0); else WAITV(2);
    __builtin_amdgcn_s_barrier();
    char* Pl = (char*)Kl + cb;         // 16KB scratch, [q(128)][kp(64)] swizzled
    {
      int q_ = w*16 + lm;
      #pragma unroll
      for (int n=0;n<4;++n)
        #pragma unroll
        for (int j=0;j<2;++j){
          uint32_t pk = cvtpk(p[n][2*j], p[n][2*j+1]);
          int kp = n*16 + lg*4 + 2*j;
          *(uint32_t*)(Pl + q_*128 + (((kp >> 3) ^ (q_ & 7))*16) + (kp & 7)*2) = pk;
        }
    }

    // ---- PV (oacc rows q = w*16+lg*4+r) ----
    __builtin_amdgcn_s_setprio(1);
    #pragma unroll
    for (int ks=0; ks<2; ++ks){
      int q_ = w*16 + lm;
      bf16x8 pf = *(const bf16x8*)(Pl + q_*128 + (((ks*4 + lg) ^ (q_ & 7))*16));
      #pragma unroll
      for (int dn=0;dn<8;++dn){
        int dd = dn*16 + lm;
        bf16x8 vf = *(const bf16x8*)((const char*)Vl + dd*128 + (((ks*4 + lg) ^ (dd & 7))*16));
        oacc[dn] = __builtin_amdgcn_mfma_f32_16x16x32_bf16(pf, vf, oacc[dn], 0,0,0);
      }
    }
    __builtin_amdgcn_s_setprio(0);

    WAITL(0);                          // all DS reads (P, V) drained for this wave
    __builtin_amdgcn_s_barrier();      // ... for ALL waves -> safe to overwrite V and Kl[cur] (P)
    if (kt + 1 < nkt) stageV(kt+1);
    if (kt + 2 < nkt) stageK(cur, kt+2);
    cur ^= 1;
  };

  for (int kt = 0; kt < nkt - 2; ++kt) iter(kt, false);   // mask-free bulk
  iter(nkt-2, true);                                      // diagonal tiles
  iter(nkt-1, true);

  // l: reduce over the 4 lg lanes (kp quarters), then redistribute to r-space
  l_run += __shfl_xor(l_run, 16, 64);
  l_run += __shfl_xor(l_run, 32, 64);
  float inv = 1.0f / l_run;
  float inv_r[4];
  #pragma unroll
  for (int r=0;r<4;++r) inv_r[r] = __shfl(inv, lg*4 + r, 64);
  #pragma unroll
  for (int dn=0;dn<8;++dn)
    #pragma unroll
    for (int r=0;r<4;++r)
      O[(size_t)(b*S_ + qrowD + r)*(H_*HD_) + h*HD_ + dn*16 + lm] = f2bf(oacc[dn][r]*inv_r[r]);
}

extern "C" void kernel_launch(void* const* d_in, const int* in_sizes, int n_in,
                              void* d_out, int out_size, void* d_ws, size_t ws_size,
                              hipStream_t stream) {
  const float* X  = (const float*)d_in[0];
  const float* Wq = (const float*)d_in[1];
  const float* Wk = (const float*)d_in[2];
  const float* Wv = (const float*)d_in[3];
  const float* Wo = (const float*)d_in[4];
  float* out = (float*)d_out;

  char* ws = (char*)d_ws;
  size_t off = 0;
  auto alloc = [&](size_t bytes)->void*{ void* p = ws + off; off += (bytes + 255) & ~(size_t)255; return p; };
  const size_t MB = (size_t)B_*S_;              // 4096
  u16* Xb   = (u16*)alloc(MB*D_*2);             // X bf16; reused as AO after projections
  u16* Wqkv = (u16*)alloc((size_t)D_*QKVN*2);   // [4608][3584] bf16: WqT | WkT | WvT; reused as Vtg later
  u16* Wot  = (u16*)alloc((size_t)H_*HD_*D_*2);
  u16* QKVb = (u16*)alloc(MB*QKVN*2);           // [4096][4608]: Q | K | V
  float* cost = (float*)alloc((size_t)S_*64*4);
  float* sint = (float*)alloc((size_t)S_*64*4);
  u16* AO  = Xb;                                // attention output, [4096][3584] bf16
  u16* Vtg = Wqkv;                              // [B][KVH][HD][S] bf16 (4.2MB <= 33MB)

  // 1. fused prep: X->bf16, 4 weight transposes, rope tables (one launch)
  prep_kernel<<<dim3(NB_CONVX + NB_WQ + NB_WK + NB_WV + NB_WO + NB_TAB), 256, 0, stream>>>(
      X, Xb, Wq, Wk, Wv, Wo, Wqkv, Wot, cost, sint);
  // 2a. Q projection + fused Q-rope+scale: 28x32 = 896 blocks, multi-block/CU
  gemm128_kernel<false, true><<<dim3(D_/128, MB/128), 256, 0, stream>>>(
      Xb, Wqkv, QKVb, (int)MB, D_, D_, QKVN, 0, cost, sint, D_, QK2SCALE);
  // 2b. KV projection + fused K-rope (cols < 512 of the KV slice): 8x32 = 256 blocks
  gemm128_kernel<false, true><<<dim3((KVH_*HD_*2)/128, MB/128), 256, 0, stream>>>(
      Xb, Wqkv + (size_t)(H_*HD_)*D_, QKVb, (int)MB, KVH_*HD_*2, D_, QKVN, H_*HD_, cost, sint, KVH_*HD_, 1.0f);
  // 3. transpose V slice: per batch [2048][512] (stride 4608) -> [512][2048]
  tbf16_kernel<<<dim3((KVH_*HD_)/32, S_/32, B_), 256, 0, stream>>>(QKVb + (H_+KVH_)*HD_, Vtg, S_, KVH_*HD_, QKVN);
  // 4. attention
  attn_kernel<<<dim3((S_/128)*H_*B_), 512, 0, stream>>>(QKVb, Vtg, AO);
  // 5. output projection (f32 out): 28x32 = 896 blocks, multi-block/CU
  gemm128_kernel<true, false><<<dim3(D_/128, MB/128), 256, 0, stream>>>(
      AO, Wot, out, (int)MB, D_, H_*HD_, D_, 0, cost, sint, 0, 1.0f);
}

// Round 20
// 399.789 us; speedup vs baseline: 1.2040x; 1.2040x over previous
//
#include <hip/hip_runtime.h>
#include <hip/hip_bf16.h>
#include <cstdint>

typedef __attribute__((ext_vector_type(8))) __bf16 bf16x8;
typedef __attribute__((ext_vector_type(4))) float f32x4;
typedef unsigned short u16;

#define B_    2
#define S_    2048
#define D_    3584
#define H_    28
#define KVH_  4
#define HD_   128
#define GQA_  7
#define QKVN  4608
// SCALE * log2(e): Q pre-scaled for exp2-domain softmax
#define QK2SCALE 0.12751744416014806f

#define WAITV(N) asm volatile("s_waitcnt vmcnt(" #N ")" ::: "memory")
#define WAITL(N) asm volatile("s_waitcnt lgkmcnt(" #N ")" ::: "memory")

__device__ __forceinline__ u16 f2bf(float f){
  union { float f; uint32_t u; } v; v.f = f;
  uint32_t u = v.u + 0x7fffu + ((v.u >> 16) & 1u);   // RNE
  return (u16)(u >> 16);
}
__device__ __forceinline__ float bf2f(u16 h){
  union { uint32_t u; float f; } v; v.u = ((uint32_t)h) << 16; return v.f;
}
__device__ __forceinline__ float exp2a(float x){       // v_exp_f32: D = 2^S0
  float r; asm("v_exp_f32 %0, %1" : "=v"(r) : "v"(x)); return r;
}
__device__ __forceinline__ uint32_t cvtpk(float lo, float hi){  // 2x f32 -> packed bf16 (RNE)
  uint32_t r; asm("v_cvt_pk_bf16_f32 %0, %1, %2" : "=v"(r) : "v"(lo), "v"(hi)); return r;
}

typedef void __attribute__((address_space(1))) as1void;
typedef void __attribute__((address_space(3))) as3void;
__device__ __forceinline__ void gload16(const void* g, void* l){
  __builtin_amdgcn_global_load_lds((as1void*)g, (as3void*)l, 16, 0, 0);
}

// ---------------- fused prep: convx | tconv x4 | rope tables, one launch ----------------
#define NB_CONVX 14336      // MB*D/4/256
#define NB_WQ    12544      // (3584/32)*(3584/32)
#define NB_WK    1792       // (512/32)*(3584/32)
#define NB_WV    1792
#define NB_WO    12544
#define NB_TAB   512        // S*64/256
__global__ __launch_bounds__(256) void prep_kernel(const float* __restrict__ X, u16* __restrict__ Xb,
                                                   const float* __restrict__ Wq, const float* __restrict__ Wk,
                                                   const float* __restrict__ Wv, const float* __restrict__ Wo,
                                                   u16* __restrict__ Wqkv, u16* __restrict__ Wot,
                                                   float* __restrict__ cost, float* __restrict__ sint){
  __shared__ float t[32][33];
  int id = blockIdx.x;
  if (id < NB_CONVX){                       // X f32 -> bf16
    int i = id*256 + threadIdx.x;
    float4 v = ((const float4*)X)[i];
    ushort4 o; o.x=f2bf(v.x); o.y=f2bf(v.y); o.z=f2bf(v.z); o.w=f2bf(v.w);
    ((ushort4*)Xb)[i] = o;
    return;
  }
  id -= NB_CONVX;
  if (id < NB_WQ + NB_WK + NB_WV + NB_WO){  // transpose+convert a weight tile
    const float* src; u16* dst; int R, C;
    if (id < NB_WQ){ src = Wq; dst = Wqkv; R = D_; C = H_*HD_; }
    else if (id < NB_WQ + NB_WK){ id -= NB_WQ; src = Wk; dst = Wqkv + (size_t)(H_*HD_)*D_; R = D_; C = KVH_*HD_; }
    else if (id < NB_WQ + NB_WK + NB_WV){ id -= NB_WQ + NB_WK; src = Wv; dst = Wqkv + (size_t)(H_*HD_ + KVH_*HD_)*D_; R = D_; C = KVH_*HD_; }
    else { id -= NB_WQ + NB_WK + NB_WV; src = Wo; dst = Wot; R = H_*HD_; C = D_; }
    int nbx = C >> 5;
    int c0 = (id % nbx) << 5, r0 = (id / nbx) << 5;
    int r = threadIdx.x >> 5, c = threadIdx.x & 31;
    #pragma unroll
    for (int i=0;i<4;i++) t[r+8*i][c] = src[(size_t)(r0 + r + 8*i)*C + c0 + c];
    __syncthreads();
    #pragma unroll
    for (int i=0;i<4;i++) dst[(size_t)(c0 + r + 8*i)*R + r0 + c] = f2bf(t[c][r+8*i]);
    return;
  }
  id -= NB_WQ + NB_WK + NB_WV + NB_WO;      // rope tables
  int i = id*256 + threadIdx.x;             // S_*64
  int s = i >> 6, d = i & 63;
  float inv = powf(1.0e6f, -(float)d * (1.0f/64.0f));
  float a = (float)s * inv;
  cost[i] = cosf(a); sint[i] = sinf(a);
}

// ---------------- transpose bf16 (V slice of QKV): per-batch [R][C] (row stride instride) -> [C][R] ----------------
__global__ __launch_bounds__(256) void tbf16_kernel(const u16* __restrict__ in, u16* __restrict__ outp, int R, int C, int instride){
  const u16* inb = in + (size_t)blockIdx.z*R*instride;
  u16* outb = outp + (size_t)blockIdx.z*R*C;
  __shared__ u16 t[32][33];
  int r = threadIdx.x >> 5, c = threadIdx.x & 31;
  int r0 = blockIdx.y*32, c0 = blockIdx.x*32;
  #pragma unroll
  for (int i=0;i<4;i++) t[r+8*i][c] = inb[(size_t)(r0+r+8*i)*instride + c0+c];
  __syncthreads();
  #pragma unroll
  for (int i=0;i<4;i++) outb[(size_t)(c0+r+8*i)*R + r0+c] = t[c][r+8*i];
}

// ---------------- 128x128 4-wave GEMM, double-buffered + counted vmcnt, K-rope epilogue ----------------
// 32KB LDS dbuf -> multi-block/CU; WAITV(4) keeps next tile's 4 gloads in flight across the barrier.
// B-fragment col map makes rope pairs (d,d+64) intra-lane: col(f) = wc*32 + (f>>1)*64 + (f&1)*16 + lm.
__global__ __launch_bounds__(256) void gemm128_kernel(const u16* __restrict__ A, const u16* __restrict__ Bt,
                                                      u16* __restrict__ C, int M, int N, int K, int ldc, int coloff,
                                                      const float* __restrict__ cost, const float* __restrict__ sint,
                                                      int ropeNmax){
  __shared__ char lds[32768];   // buf c at c*16384: A[128][32] (8KB) | B[128][32] (8KB)
  const int tid = threadIdx.x;
  const int l = tid & 63, lg = l >> 4, lm = l & 15;
  const int w = tid >> 6, wr = w >> 1, wc = w & 1;
  const int m0 = blockIdx.y * 128, n0 = blockIdx.x * 128;

  f32x4 acc[4][4];
  #pragma unroll
  for (int m=0;m<4;++m)
    #pragma unroll
    for (int n=0;n<4;++n) acc[m][n] = (f32x4){0.f,0.f,0.f,0.f};

  auto stage = [&](int T){      // 4 gloads
    const int kb = T << 5;
    char* base = lds + (size_t)(T & 1)*16384;
    #pragma unroll
    for (int j = 0; j < 2; ++j){
      int g = j*256 + tid;
      int row = g >> 2, wi = g & 3;
      int ksrc = kb + ((wi ^ (row & 3)) << 3);
      gload16(A  + (size_t)(m0+row)*K + ksrc, base + j*4096 + (tid & 192)*16);
      gload16(Bt + (size_t)(n0+row)*K + ksrc, base + 8192 + j*4096 + (tid & 192)*16);
    }
  };

  const int nkt = K >> 5;
  stage(0); stage(1);           // 8 loads outstanding
  int cur = 0;
  for (int t = 0; t < nkt; ++t){
    if (t + 1 < nkt){ WAITV(4); }   // tile t landed; t+1's 4 in flight
    else            { WAITV(0); }
    __builtin_amdgcn_s_barrier();
    const char* As = lds + (size_t)cur*16384;
    const char* Bs = As + 8192;
    bf16x8 af[4], bfr[4];
    #pragma unroll
    for (int m = 0; m < 4; ++m){
      int r = wr*64 + m*16 + lm;
      af[m] = *(const bf16x8*)(As + r*64 + ((lg ^ (r & 3)) << 4));
    }
    #pragma unroll
    for (int n = 0; n < 4; ++n){
      int r = (wc<<5) + ((n>>1)<<6) + ((n&1)<<4) + lm;
      bfr[n] = *(const bf16x8*)(Bs + r*64 + ((lg ^ (r & 3)) << 4));
    }
    __builtin_amdgcn_s_setprio(1);
    #pragma unroll
    for (int m = 0; m < 4; ++m)
      #pragma unroll
      for (int n = 0; n < 4; ++n)
        acc[m][n] = __builtin_amdgcn_mfma_f32_16x16x32_bf16(af[m], bfr[n], acc[m][n], 0,0,0);
    __builtin_amdgcn_s_setprio(0);
    WAITL(0);                       // this wave's ds reads drained
    __builtin_amdgcn_s_barrier();   // all waves -> safe to overwrite buf[cur]
    if (t + 2 < nkt) stage(t+2);
    cur ^= 1;
  }

  // K-rope epilogue (no scale): pairs acc[m][n]/acc[m][n+2], d = wc*32 + n*16 + lm
  if (n0 < ropeNmax){
    #pragma unroll
    for (int m=0;m<4;++m)
      #pragma unroll
      for (int n=0;n<2;++n)
        #pragma unroll
        for (int r=0;r<4;++r){
          int row = m0 + wr*64 + m*16 + lg*4 + r;
          int s = row & (S_-1);
          int d = (wc<<5) + (n<<4) + lm;
          float cv = cost[s*64+d], sv = sint[s*64+d];
          float lo = acc[m][n][r], hi = acc[m][n+2][r];
          acc[m][n][r]   = lo*cv - hi*sv;
          acc[m][n+2][r] = hi*cv + lo*sv;
        }
  }

  #pragma unroll
  for (int m=0;m<4;++m)
    #pragma unroll
    for (int n=0;n<4;++n)
      #pragma unroll
      for (int r=0;r<4;++r){
        int row = m0 + wr*64 + m*16 + lg*4 + r;
        int col = coloff + n0 + (wc<<5) + ((n>>1)<<6) + ((n&1)<<4) + lm;
        C[(size_t)row*ldc + col] = f2bf(acc[m][n][r]);
      }
}

// ---------------- 256x256 4-phase GEMM (r12 schedule) + optional Q-rope epilogue ----------------
template<bool OUTF32, bool ROPEQ>
__global__ __launch_bounds__(512) void gemm256_kernel(const u16* __restrict__ A, const u16* __restrict__ Bt,
                                                      void* __restrict__ Cv, int M, int N, int K, int nbx,
                                                      int ldc, int coloff,
                                                      const float* __restrict__ cost, const float* __restrict__ sint){
  extern __shared__ char lds[];   // 131072 bytes
  const int tid = threadIdx.x;
  const int l = tid & 63, lg = l >> 4, lm = l & 15;
  const int w = tid >> 6, wr = w >> 2, wc = w & 3;
  const int srow = tid >> 3, swi = tid & 7;

  // XCD-bijective block swizzle (m204)
  const int nwg = (int)gridDim.x;
  const int q8 = nwg >> 3, r8 = nwg & 7;
  const int xcd = blockIdx.x & 7, pos = blockIdx.x >> 3;
  const int wg = (xcd < r8 ? xcd*(q8+1) : r8*(q8+1) + (xcd - r8)*q8) + pos;
  const int m0 = (wg / nbx) * 256, n0 = (wg % nbx) * 256;

  f32x4 acc[8][4];
  #pragma unroll
  for (int m=0;m<8;++m)
    #pragma unroll
    for (int n=0;n<4;++n) acc[m][n] = (f32x4){0.f,0.f,0.f,0.f};
  bf16x8 aF[8][2], bF[4][2];

  auto stage = [&](int T, int ht){
    const u16* p = (ht < 2) ? (A + (size_t)(m0 + (ht << 7))*K)
                            : (Bt + (size_t)(n0 + ((ht - 2) << 7))*K);
    char* d = lds + ((size_t)(T & 1) << 16) + (ht << 14) + ((tid & 448) << 4);
    #pragma unroll
    for (int j = 0; j < 2; ++j){
      int r = (j << 6) + srow;
      gload16(p + (size_t)r*K + (size_t)T*64 + ((swi ^ (r & 7)) << 3), d + (j << 13));
    }
  };
  auto ldA = [&](int c, int mh){
    const char* base = lds + (c << 16) + (wr << 14);
    #pragma unroll
    for (int m = 0; m < 4; ++m){
      int r = ((mh*4 + m) << 4) + lm;
      #pragma unroll
      for (int kk = 0; kk < 2; ++kk)
        aF[mh*4+m][kk] = *(const bf16x8*)(base + r*128 + (((kk*4 + lg) ^ (r & 7)) << 4));
    }
  };
  auto ldB = [&](int c, int nh){
    #pragma unroll
    for (int n = 0; n < 2; ++n){
      int f = nh*2 + n;
      int rb = ((wc>>1)<<7) + ((wc&1)<<5) + ((f>>1)<<6) + ((f&1)<<4) + lm;
      const char* base = lds + (c << 16) + 32768 + ((rb >> 7) << 14);
      int ri = rb & 127;
      #pragma unroll
      for (int kk = 0; kk < 2; ++kk)
        bF[f][kk] = *(const bf16x8*)(base + ri*128 + (((kk*4 + lg) ^ (ri & 7)) << 4));
    }
  };
  auto mmaQ = [&](int mh, int nh){
    __builtin_amdgcn_s_setprio(1);
    #pragma unroll
    for (int m = 0; m < 4; ++m)
      #pragma unroll
      for (int n = 0; n < 2; ++n)
        #pragma unroll
        for (int kk = 0; kk < 2; ++kk)
          acc[mh*4+m][nh*2+n] = __builtin_amdgcn_mfma_f32_16x16x32_bf16(
              aF[mh*4+m][kk], bF[nh*2+n][kk], acc[mh*4+m][nh*2+n], 0,0,0);
    __builtin_amdgcn_s_setprio(0);
  };

  const int nkt = K >> 6;
  stage(0,0); stage(0,1); stage(0,2); stage(0,3);
  stage(1,2); stage(1,0); stage(1,1);
  WAITV(6);
  __builtin_amdgcn_s_barrier();

  for (int t = 0; t < nkt; ++t){
    const int c = t & 1;
    ldA(c,0); ldB(c,0); ldB(c,1);
    if (t + 1 < nkt) stage(t+1, 3);
    WAITL(4);
    __builtin_amdgcn_s_barrier();
    mmaQ(0,0);
    WAITL(0);
    __builtin_amdgcn_s_barrier();
    ldA(c,1);
    if (t + 2 < nkt) stage(t+2, 2);
    __builtin_amdgcn_s_barrier();
    mmaQ(0,1);
    WAITL(0);
    __builtin_amdgcn_s_barrier();
    if (t + 2 < nkt) stage(t+2, 0);
    __builtin_amdgcn_s_barrier();
    mmaQ(1,0);
    __builtin_amdgcn_s_barrier();
    if (t + 2 < nkt){ stage(t+2, 1); WAITV(6); }
    else if (t + 1 < nkt){ WAITV(0); }
    __builtin_amdgcn_s_barrier();
    mmaQ(1,1);
    __builtin_amdgcn_s_barrier();
  }

  // Q-rope epilogue (with QK2SCALE): pairs acc[m][n]/acc[m][n+2], d = (wc&1)*32 + n*16 + lm
  if (ROPEQ){
    #pragma unroll
    for (int m=0;m<8;++m)
      #pragma unroll
      for (int n=0;n<2;++n)
        #pragma unroll
        for (int r=0;r<4;++r){
          int row = m0 + wr*128 + m*16 + lg*4 + r;
          int s = row & (S_-1);
          int d = ((wc&1)<<5) + (n<<4) + lm;
          float cv = cost[s*64+d], sv = sint[s*64+d];
          float lo = acc[m][n][r], hi = acc[m][n+2][r];
          acc[m][n][r]   = (lo*cv - hi*sv)*QK2SCALE;
          acc[m][n+2][r] = (hi*cv + lo*sv)*QK2SCALE;
        }
  }

  #pragma unroll
  for (int m = 0; m < 8; ++m)
    #pragma unroll
    for (int n = 0; n < 4; ++n)
      #pragma unroll
      for (int r = 0; r < 4; ++r){
        int row = m0 + wr*128 + m*16 + lg*4 + r;
        int col = coloff + n0 + ((wc>>1)<<7) + ((wc&1)<<5) + ((n>>1)<<6) + ((n&1)<<4) + lm;
        if (OUTF32) ((float*)Cv)[(size_t)row*ldc + col] = acc[m][n][r];
        else        ((u16*)Cv)[(size_t)row*ldc + col] = f2bf(acc[m][n][r]);
      }
}

// ---------------- flash attention, causal, GQA (round-17 structure, unchanged) ----------------
__global__ __launch_bounds__(512, 4) void attn_kernel(const u16* __restrict__ QKV, const u16* __restrict__ Vt,
                                                      u16* __restrict__ O){
  __shared__ u16 Kl[2][8192];   // [buf][kp(64)][d(128)], XOR-swizzled granules (16/row, ^kp&7)
  __shared__ u16 Vl[8192];      // [d(128)][kp(64)], swizzled (8/row, ^d&7), single buffer
  const int id = blockIdx.x;
  const int qt = (S_/128 - 1) - id/(H_*B_);     // reversed: heavy tiles dispatch first
  const int hb = id % (H_*B_);
  const int h = hb % H_, b = hb / H_;
  const int kvh = h / GQA_;
  const int tid = threadIdx.x;
  const int w = tid >> 6, l = tid & 63, lg = l >> 4, lm = l & 15;

  const int qrowA = qt*128 + w*16 + lm;       // the q-row whose fragment this lane carries
  const u16* qptr = QKV + (size_t)(b*S_ + qrowA)*QKVN + h*HD_;
  bf16x8 qf[4];
  #pragma unroll
  for (int ks = 0; ks < 4; ++ks) qf[ks] = *(const bf16x8*)(qptr + ks*32 + lg*8);
  WAITV(0);
  asm volatile("" :: "v"(qf[0]), "v"(qf[1]), "v"(qf[2]), "v"(qf[3]));

  const int qcol  = qrowA;                    // this lane's q in swapped-S space
  const int qrowD = qt*128 + w*16 + lg*4;     // output rows (PV D-layout), +r
  float m_run = -3.0e38f, l_run = 0.0f;
  f32x4 oacc[8];
  #pragma unroll
  for (int dn=0;dn<8;++dn) oacc[dn] = (f32x4){0.f,0.f,0.f,0.f};

  const u16* Kbase = QKV + (size_t)(b*S_)*QKVN + H_*HD_ + kvh*HD_;
  const u16* Vbase = Vt + (size_t)(b*KVH_ + kvh)*HD_*S_;

  auto stageK = [&](int bufi, int ktv){
    const int kb = ktv*64;
    #pragma unroll
    for (int j = 0; j < 2; ++j){
      int g = j*512 + tid;
      int kp = g >> 4, wik = g & 15;
      gload16(Kbase + (size_t)(kb + kp)*QKVN + (wik ^ (kp & 7))*8,
              (char*)Kl + bufi*16384 + j*8192 + (tid & 448)*16);
    }
  };
  auto stageV = [&](int ktv){
    const int kb = ktv*64;
    #pragma unroll
    for (int j = 0; j < 2; ++j){
      int g = j*512 + tid;
      int dd = g >> 3, wiv = g & 7;
      gload16(Vbase + (size_t)dd*S_ + kb + (wiv ^ (dd & 7))*8,
              (char*)Vl + j*8192 + (tid & 448)*16);
    }
  };

  const int nkt = 2*qt + 2;
  int cur = 0;
  stageK(0, 0); stageV(0); stageK(1, 1);

  auto iter = [&](int kt, bool domask){
    const bool last = (kt + 1 == nkt);
    // top: drain K(kt) only; V(kt) and K(kt+1) remain in flight
    if (last) WAITV(2); else WAITV(4);
    __builtin_amdgcn_s_barrier();
    const int cb = cur*16384;

    // ---- QK^T, SWAPPED: sf[n][r] = S[kp = n*16+lg*4+r][q = qcol] ----
    f32x4 sf[4];
    __builtin_amdgcn_s_setprio(1);
    #pragma unroll
    for (int n = 0; n < 4; ++n){
      sf[n] = (f32x4){0.f,0.f,0.f,0.f};
      int kp = n*16 + lm;
      #pragma unroll
      for (int ks = 0; ks < 4; ++ks){
        bf16x8 kf = *(const bf16x8*)((const char*)Kl + cb + kp*256 + (((ks*4 + lg) ^ (kp & 7))*16));
        sf[n] = __builtin_amdgcn_mfma_f32_16x16x32_bf16(kf, qf[ks], sf[n], 0,0,0);
      }
    }
    __builtin_amdgcn_s_setprio(0);

    // ---- softmax: lane owns 16 scores of row q=qcol ----
    float p[4][4];
    float rmax = -3.0e38f;
    #pragma unroll
    for (int n=0;n<4;++n)
      #pragma unroll
      for (int r=0;r<4;++r){
        float v = sf[n][r];
        if (domask && (kt*64 + n*16 + lg*4 + r) > qcol) v -= 1.0e9f;
        p[n][r] = v;
        rmax = fmaxf(rmax, v);
      }
    rmax = fmaxf(rmax, __shfl_xor(rmax, 16, 64));
    rmax = fmaxf(rmax, __shfl_xor(rmax, 32, 64));

    // thresholded defer-max: rescale only when growth exceeds 8 (exp2 domain)
    if (__any(rmax > m_run + 8.0f)){
      float mn = fmaxf(m_run, rmax);
      float corr = exp2a(m_run - mn);
      m_run = mn;
      l_run *= corr;
      float corr_r[4];
      #pragma unroll
      for (int r=0;r<4;++r) corr_r[r] = __shfl(corr, lg*4 + r, 64);
      #pragma unroll
      for (int dn=0;dn<8;++dn)
        #pragma unroll
        for (int r=0;r<4;++r) oacc[dn][r] *= corr_r[r];
    }
    float psum = 0.f;
    #pragma unroll
    for (int n=0;n<4;++n)
      #pragma unroll
      for (int r=0;r<4;++r){ p[n][r] = exp2a(p[n][r] - m_run); psum += p[n][r]; }
    l_run += psum;

    // ---- V(kt) drained (own loads), then barrier: Kl[cur] dead for aliasing AND all waves' V visible ----
    if (last) WAITV(0); else WAITV(2);
    __builtin_amdgcn_s_barrier();
    char* Pl = (char*)Kl + cb;         // 16KB scratch, [q(128)][kp(64)] swizzled
    {
      int q_ = w*16 + lm;
      #pragma unroll
      for (int n=0;n<4;++n)
        #pragma unroll
        for (int j=0;j<2;++j){
          uint32_t pk = cvtpk(p[n][2*j], p[n][2*j+1]);
          int kp = n*16 + lg*4 + 2*j;
          *(uint32_t*)(Pl + q_*128 + (((kp >> 3) ^ (q_ & 7))*16) + (kp & 7)*2) = pk;
        }
    }

    // ---- PV (oacc rows q = w*16+lg*4+r) ----
    __builtin_amdgcn_s_setprio(1);
    #pragma unroll
    for (int ks=0; ks<2; ++ks){
      int q_ = w*16 + lm;
      bf16x8 pf = *(const bf16x8*)(Pl + q_*128 + (((ks*4 + lg) ^ (q_ & 7))*16));
      #pragma unroll
      for (int dn=0;dn<8;++dn){
        int dd = dn*16 + lm;
        bf16x8 vf = *(const bf16x8*)((const char*)Vl + dd*128 + (((ks*4 + lg) ^ (dd & 7))*16));
        oacc[dn] = __builtin_amdgcn_mfma_f32_16x16x32_bf16(pf, vf, oacc[dn], 0,0,0);
      }
    }
    __builtin_amdgcn_s_setprio(0);

    WAITL(0);                          // all DS reads (P, V) drained for this wave
    __builtin_amdgcn_s_barrier();      // ... for ALL waves -> safe to overwrite V and Kl[cur] (P)
    if (kt + 1 < nkt) stageV(kt+1);
    if (kt + 2 < nkt) stageK(cur, kt+2);
    cur ^= 1;
  };

  for (int kt = 0; kt < nkt - 2; ++kt) iter(kt, false);   // mask-free bulk
  iter(nkt-2, true);                                      // diagonal tiles
  iter(nkt-1, true);

  // l: reduce over the 4 lg lanes (kp quarters), then redistribute to r-space
  l_run += __shfl_xor(l_run, 16, 64);
  l_run += __shfl_xor(l_run, 32, 64);
  float inv = 1.0f / l_run;
  float inv_r[4];
  #pragma unroll
  for (int r=0;r<4;++r) inv_r[r] = __shfl(inv, lg*4 + r, 64);
  #pragma unroll
  for (int dn=0;dn<8;++dn)
    #pragma unroll
    for (int r=0;r<4;++r)
      O[(size_t)(b*S_ + qrowD + r)*(H_*HD_) + h*HD_ + dn*16 + lm] = f2bf(oacc[dn][r]*inv_r[r]);
}

extern "C" void kernel_launch(void* const* d_in, const int* in_sizes, int n_in,
                              void* d_out, int out_size, void* d_ws, size_t ws_size,
                              hipStream_t stream) {
  const float* X  = (const float*)d_in[0];
  const float* Wq = (const float*)d_in[1];
  const float* Wk = (const float*)d_in[2];
  const float* Wv = (const float*)d_in[3];
  const float* Wo = (const float*)d_in[4];
  float* out = (float*)d_out;

  char* ws = (char*)d_ws;
  size_t off = 0;
  auto alloc = [&](size_t bytes)->void*{ void* p = ws + off; off += (bytes + 255) & ~(size_t)255; return p; };
  const size_t MB = (size_t)B_*S_;              // 4096
  u16* Xb   = (u16*)alloc(MB*D_*2);             // X bf16; reused as AO after projections
  u16* Wqkv = (u16*)alloc((size_t)D_*QKVN*2);   // [4608][3584] bf16: WqT | WkT | WvT; reused as Vtg later
  u16* Wot  = (u16*)alloc((size_t)H_*HD_*D_*2);
  u16* QKVb = (u16*)alloc(MB*QKVN*2);           // [4096][4608]: Q | K | V
  float* cost = (float*)alloc((size_t)S_*64*4);
  float* sint = (float*)alloc((size_t)S_*64*4);
  u16* AO  = Xb;                                // attention output, [4096][3584] bf16
  u16* Vtg = Wqkv;                              // [B][KVH][HD][S] bf16 (4.2MB <= 33MB)

  (void)hipFuncSetAttribute(reinterpret_cast<const void*>(gemm256_kernel<false, true>),
                            hipFuncAttributeMaxDynamicSharedMemorySize, 131072);
  (void)hipFuncSetAttribute(reinterpret_cast<const void*>(gemm256_kernel<true, false>),
                            hipFuncAttributeMaxDynamicSharedMemorySize, 131072);

  // 1. fused prep: X->bf16, 4 weight transposes, rope tables (one launch)
  prep_kernel<<<dim3(NB_CONVX + NB_WQ + NB_WK + NB_WV + NB_WO + NB_TAB), 256, 0, stream>>>(
      X, Xb, Wq, Wk, Wv, Wo, Wqkv, Wot, cost, sint);
  // 2a. Q projection + fused Q-rope+scale: 224 blocks -> one round
  gemm256_kernel<false, true><<<dim3((D_/256)*(MB/256)), 512, 131072, stream>>>(
      Xb, Wqkv, QKVb, (int)MB, D_, D_, D_/256, QKVN, 0, cost, sint);
  // 2b. KV projection + fused K-rope (cols < 512 of the KV slice): 256 blocks, dbuf pipeline
  gemm128_kernel<<<dim3((KVH_*HD_*2)/128, MB/128), 256, 0, stream>>>(
      Xb, Wqkv + (size_t)(H_*HD_)*D_, QKVb, (int)MB, KVH_*HD_*2, D_, QKVN, H_*HD_, cost, sint, KVH_*HD_);
  // 3. transpose V slice: per batch [2048][512] (stride 4608) -> [512][2048]
  tbf16_kernel<<<dim3((KVH_*HD_)/32, S_/32, B_), 256, 0, stream>>>(QKVb + (H_+KVH_)*HD_, Vtg, S_, KVH_*HD_, QKVN);
  // 4. attention
  attn_kernel<<<dim3((S_/128)*H_*B_), 512, 0, stream>>>(QKVb, Vtg, AO);
  // 5. output projection (f32 out): 224 blocks -> one round
  gemm256_kernel<true, false><<<dim3((D_/256)*(MB/256)), 512, 131072, stream>>>(
      AO, Wot, out, (int)MB, D_, H_*HD_, D_/256, D_, 0, cost, sint);
}